// Round 2
// baseline (597.556 us; speedup 1.0000x reference)
//
#include <hip/hip_runtime.h>
#include <hip/hip_bf16.h>
#include <cstdint>
#include <cstddef>

#define B_ 64
#define S_ 2048
#define H_ 512

typedef __bf16 bf16x8 __attribute__((ext_vector_type(8)));
typedef float  f32x4  __attribute__((ext_vector_type(4)));

#define AS_GLB __attribute__((address_space(1)))
#define AS_LDS __attribute__((address_space(3)))

__device__ __forceinline__ float fast_tanh(float x) {
    float e = __expf(2.0f * x);
    return 1.0f - __fdividef(2.0f, e + 1.0f);
}

// ---------------------------------------------------------------------------
// W1 [k][n] f32  ->  Wt [n][k] bf16   (transpose + downcast, LDS-tiled)
// ---------------------------------------------------------------------------
__global__ __launch_bounds__(256) void w1t_kernel(const float* __restrict__ W1,
                                                  unsigned short* __restrict__ Wt) {
    __shared__ float tile[32][33];
    int tn = blockIdx.x >> 4;   // n-tile  (16)
    int tk = blockIdx.x & 15;   // k-tile  (16)
    int lx = threadIdx.x & 31;
    int ly = threadIdx.x >> 5;  // 0..7
#pragma unroll
    for (int i = 0; i < 4; ++i) {
        int k = tk * 32 + ly + i * 8;
        tile[ly + i * 8][lx] = W1[k * H_ + tn * 32 + lx];   // coalesced read
    }
    __syncthreads();
#pragma unroll
    for (int i = 0; i < 4; ++i) {
        int n = tn * 32 + ly + i * 8;
        float v = tile[lx][ly + i * 8];                      // W1[tk*32+lx][n]
        __bf16 bv = (__bf16)v;
        Wt[(size_t)n * H_ + tk * 32 + lx] = *(unsigned short*)&bv;  // coalesced write
    }
}

// ---------------------------------------------------------------------------
// cvals[b][h] = b1[h] + b2[h] + sum_k hidden[b][k] * W2[k][h]
// ---------------------------------------------------------------------------
__global__ __launch_bounds__(512) void hidproj_kernel(const float* __restrict__ hidden,
                                                      const float* __restrict__ W2,
                                                      const float* __restrict__ b1,
                                                      const float* __restrict__ b2,
                                                      float* __restrict__ cvals) {
    int b = blockIdx.x;
    int h = threadIdx.x;
    float acc = b1[h] + b2[h];
    const float* hp = hidden + b * H_;
    const float* wp = W2 + h;
#pragma unroll 8
    for (int k = 0; k < H_; ++k) acc = fmaf(hp[k], wp[(size_t)k * H_], acc);
    cvals[b * H_ + h] = acc;
}

// ---------------------------------------------------------------------------
// Fused: logits[b][s] += sum_{h in ntile} V[h] * tanh((enc@W1)[b,s,h] + cvals[b,h])
// 128x128 tile, K=512, BK=64, 4 waves, bf16 MFMA 16x16x32.
// A (enc f32) reg-staged with convert; B (Wt bf16) via global_load_lds.
// ---------------------------------------------------------------------------
__global__ __launch_bounds__(256) void score_kernel(const float* __restrict__ enc,
                                                    const unsigned short* __restrict__ Wt,
                                                    const float* __restrict__ cvals,
                                                    const float* __restrict__ Vp,
                                                    float* __restrict__ logits) {
    __shared__ unsigned short As[2][128][64];
    __shared__ unsigned short Bs[2][128][64];   // Bs[n][k]

    // XCD-bijective swizzle: 4096 % 8 == 0
    int orig = blockIdx.x;
    int wg   = (orig & 7) * 512 + (orig >> 3);
    int b     = wg >> 6;
    int stile = (wg >> 2) & 15;
    int ntile = wg & 3;

    int tid  = threadIdx.x;
    int wid  = tid >> 6;
    int lane = tid & 63;
    int wm = wid >> 1, wn = wid & 1;

    f32x4 acc[4][4];
#pragma unroll
    for (int m = 0; m < 4; ++m)
#pragma unroll
        for (int n = 0; n < 4; ++n) acc[m][n] = (f32x4){0.f, 0.f, 0.f, 0.f};

    const float* Abase = enc + ((size_t)(b * S_ + stile * 128)) * H_;
    float4 ra[4][2];

    auto stageA_load = [&](int kt) {
        int kk = kt * 64;
#pragma unroll
        for (int i = 0; i < 4; ++i) {
            int slot = tid + i * 256;
            int row  = slot >> 3;
            int c0   = (slot & 7) * 8;
            const float* p = Abase + (size_t)row * H_ + kk + c0;
            ra[i][0] = *(const float4*)p;
            ra[i][1] = *(const float4*)(p + 4);
        }
    };
    auto stageA_write = [&](int nb) {
#pragma unroll
        for (int i = 0; i < 4; ++i) {
            int slot = tid + i * 256;
            int row  = slot >> 3;
            int c0   = (slot & 7) * 8;
            bf16x8 v;
            const float* f = (const float*)&ra[i][0];
#pragma unroll
            for (int j = 0; j < 8; ++j) v[j] = (__bf16)f[j];
            *(bf16x8*)&As[nb][row][c0] = v;
        }
    };
    auto stageB = [&](int nb, int kt) {
        int kk = kt * 64;
#pragma unroll
        for (int i = 0; i < 4; ++i) {
            int chunk = wid * 4 + i;                 // 0..15
            int n  = chunk * 8 + (lane >> 3);
            int c0 = (lane & 7) * 8;
            const unsigned short* src = Wt + (size_t)(ntile * 128 + n) * H_ + kk + c0;
            __builtin_amdgcn_global_load_lds((const AS_GLB unsigned int*)src,
                                             (AS_LDS unsigned int*)&Bs[nb][chunk * 8][0],
                                             16, 0, 0);
        }
    };
    auto compute = [&](int cb) {
#pragma unroll
        for (int ks = 0; ks < 2; ++ks) {
            int kof  = ks * 32 + (lane >> 4) * 8;
            int rsel = lane & 15;
            bf16x8 af[4], bfr[4];
#pragma unroll
            for (int m = 0; m < 4; ++m)
                af[m] = *(const bf16x8*)&As[cb][wm * 64 + m * 16 + rsel][kof];
#pragma unroll
            for (int n = 0; n < 4; ++n)
                bfr[n] = *(const bf16x8*)&Bs[cb][wn * 64 + n * 16 + rsel][kof];
#pragma unroll
            for (int m = 0; m < 4; ++m)
#pragma unroll
                for (int n = 0; n < 4; ++n)
                    acc[m][n] = __builtin_amdgcn_mfma_f32_16x16x32_bf16(
                        af[m], bfr[n], acc[m][n], 0, 0, 0);
        }
    };

    // prologue
    stageA_load(0);
    stageA_write(0);
    stageB(0, 0);
    __syncthreads();

    for (int kt = 0; kt < 8; ++kt) {
        int cur = kt & 1;
        if (kt < 7) {
            stageA_load(kt + 1);
            stageB(cur ^ 1, kt + 1);
        }
        compute(cur);
        if (kt < 7) stageA_write(cur ^ 1);
        __syncthreads();
    }

    // epilogue: tanh + V-dot + row reduce + atomic partial logits
    int csel = lane & 15;
    float cw[4], vv[4];
#pragma unroll
    for (int n = 0; n < 4; ++n) {
        int col = ntile * 128 + wn * 64 + n * 16 + csel;
        cw[n] = cvals[b * H_ + col];
        vv[n] = Vp[col];
    }
    float part[16];
#pragma unroll
    for (int m = 0; m < 4; ++m)
#pragma unroll
        for (int r = 0; r < 4; ++r) {
            float p = 0.f;
#pragma unroll
            for (int n = 0; n < 4; ++n) {
                float s = fast_tanh(acc[m][n][r] + cw[n]);
                p = fmaf(vv[n], s, p);
            }
            part[m * 4 + r] = p;
        }
#pragma unroll
    for (int i = 0; i < 16; ++i)
#pragma unroll
        for (int off = 1; off < 16; off <<= 1)
            part[i] += __shfl_xor(part[i], off);

    if (csel == 0) {
        int g = lane >> 4;
#pragma unroll
        for (int m = 0; m < 4; ++m)
#pragma unroll
            for (int r = 0; r < 4; ++r) {
                int row = stile * 128 + wm * 64 + m * 16 + g * 4 + r;
                atomicAdd(&logits[b * S_ + row], part[m * 4 + r]);
            }
    }
}

// ---------------------------------------------------------------------------
// softmax over s per b
// ---------------------------------------------------------------------------
__global__ __launch_bounds__(256) void softmax_kernel(const float* __restrict__ logits,
                                                      float* __restrict__ wout) {
    int b = blockIdx.x;
    int t = threadIdx.x;
    __shared__ float red[8];
    float v[8];
#pragma unroll
    for (int i = 0; i < 8; ++i) v[i] = logits[b * S_ + t + i * 256];
    float m = v[0];
#pragma unroll
    for (int i = 1; i < 8; ++i) m = fmaxf(m, v[i]);
#pragma unroll
    for (int off = 32; off >= 1; off >>= 1) m = fmaxf(m, __shfl_xor(m, off));
    int wid = t >> 6, lane = t & 63;
    if (lane == 0) red[wid] = m;
    __syncthreads();
    m = fmaxf(fmaxf(red[0], red[1]), fmaxf(red[2], red[3]));
    float s = 0.f;
#pragma unroll
    for (int i = 0; i < 8; ++i) { v[i] = __expf(v[i] - m); s += v[i]; }
#pragma unroll
    for (int off = 32; off >= 1; off >>= 1) s += __shfl_xor(s, off);
    if (lane == 0) red[4 + wid] = s;
    __syncthreads();
    float tot = red[4] + red[5] + red[6] + red[7];
    float inv = __fdividef(1.0f, tot);
#pragma unroll
    for (int i = 0; i < 8; ++i) wout[b * S_ + t + i * 256] = v[i] * inv;
}

// ---------------------------------------------------------------------------
// context[b][h] = sum_s w[b][s] * enc[b][s][h]
// ---------------------------------------------------------------------------
__global__ __launch_bounds__(512) void context_kernel(const float* __restrict__ enc,
                                                      const float* __restrict__ w,
                                                      float* __restrict__ ctx) {
    int b  = blockIdx.x >> 4;
    int sc = blockIdx.x & 15;
    int h  = threadIdx.x;
    const float* ep = enc + ((size_t)(b * S_ + sc * 128)) * H_ + h;
    const float* wp = w + b * S_ + sc * 128;
    float acc = 0.f;
#pragma unroll 4
    for (int i = 0; i < 128; ++i) acc = fmaf(wp[i], ep[(size_t)i * H_], acc);
    atomicAdd(&ctx[b * H_ + h], acc);
}

// ---------------------------------------------------------------------------
extern "C" void kernel_launch(void* const* d_in, const int* in_sizes, int n_in,
                              void* d_out, int out_size, void* d_ws, size_t ws_size,
                              hipStream_t stream) {
    (void)in_sizes; (void)n_in; (void)out_size; (void)ws_size;
    const float* enc    = (const float*)d_in[0];
    const float* hidden = (const float*)d_in[1];
    const float* W1     = (const float*)d_in[2];
    const float* b1     = (const float*)d_in[3];
    const float* W2     = (const float*)d_in[4];
    const float* b2     = (const float*)d_in[5];
    const float* Vp     = (const float*)d_in[6];
    // d_in[7] (bV) unused: softmax is shift-invariant and logits are not an output.

    char* ws = (char*)d_ws;
    unsigned short* Wt = (unsigned short*)ws;                    // 512 KB
    float* cvals  = (float*)(ws + 524288);                       // 128 KB
    float* logits = (float*)(ws + 524288 + 131072);              // 512 KB

    float* ctx  = (float*)d_out;          // [64,512]
    float* wout = ctx + B_ * H_;          // [64,2048,1]

    hipMemsetAsync(logits, 0, (size_t)B_ * S_ * sizeof(float), stream);
    hipMemsetAsync(ctx,    0, (size_t)B_ * H_ * sizeof(float), stream);

    w1t_kernel<<<256, 256, 0, stream>>>(W1, Wt);
    hidproj_kernel<<<64, 512, 0, stream>>>(hidden, W2, b1, b2, cvals);
    score_kernel<<<4096, 256, 0, stream>>>(enc, Wt, cvals, Vp, logits);
    softmax_kernel<<<64, 256, 0, stream>>>(logits, wout);
    context_kernel<<<1024, 512, 0, stream>>>(enc, wout, ctx);
}